// Round 2
// baseline (83.029 us; speedup 1.0000x reference)
//
#include <hip/hip_runtime.h>

// Problem constants (pinned by the reference)
#define UNITS     49152
#define INPUT_DIM 15
#define BATCH     2048

constexpr int TPB            = 256;
constexpr int U_PER_THREAD   = 4;                     // float4 along U
constexpr int U_PER_BLOCK    = TPB * U_PER_THREAD;    // 1024
constexpr int ROWS_PER_BLOCK = 64;                    // batch rows per block

typedef float f32x4 __attribute__((ext_vector_type(4)));

__global__ __launch_bounds__(TPB) void striatum_kernel(
    const float* __restrict__ x,     // [BATCH, INPUT_DIM]
    const float* __restrict__ w,     // [INPUT_DIM, UNITS]
    const float* __restrict__ bias,  // [UNITS]
    const float* __restrict__ mask,  // [UNITS, INPUT_DIM]
    float* __restrict__ out)         // [BATCH, UNITS]
{
    __shared__ float xs[ROWS_PER_BLOCK * INPUT_DIM];  // 960 floats = 3.84 KB

    const int u0   = blockIdx.x * U_PER_BLOCK + threadIdx.x * U_PER_THREAD;
    const int row0 = blockIdx.y * ROWS_PER_BLOCK;

    // Cooperative load of the x row-tile into LDS (960 elements over 256 threads)
    for (int idx = threadIdx.x; idx < ROWS_PER_BLOCK * INPUT_DIM; idx += TPB) {
        xs[idx] = x[row0 * INPUT_DIM + idx];
    }

    // Pre-mask this thread's 4 weight columns into registers: mw[i] = w[i, u0..u0+3] * mask[u0..u0+3, i]
    f32x4 mw[INPUT_DIM];
#pragma unroll
    for (int i = 0; i < INPUT_DIM; ++i) {
        f32x4 wv = *reinterpret_cast<const f32x4*>(&w[(size_t)i * UNITS + u0]);
        wv.x *= mask[(size_t)(u0 + 0) * INPUT_DIM + i];
        wv.y *= mask[(size_t)(u0 + 1) * INPUT_DIM + i];
        wv.z *= mask[(size_t)(u0 + 2) * INPUT_DIM + i];
        wv.w *= mask[(size_t)(u0 + 3) * INPUT_DIM + i];
        mw[i] = wv;
    }
    const f32x4 bv = *reinterpret_cast<const f32x4*>(&bias[u0]);

    __syncthreads();

    // Stream ROWS_PER_BLOCK output rows; weights stay in registers.
    for (int r = 0; r < ROWS_PER_BLOCK; ++r) {
        const float* xr = &xs[r * INPUT_DIM];   // broadcast reads (same addr all lanes)
        f32x4 acc = bv;
#pragma unroll
        for (int i = 0; i < INPUT_DIM; ++i) {
            const float xv = xr[i];
            acc.x = fmaf(xv, mw[i].x, acc.x);
            acc.y = fmaf(xv, mw[i].y, acc.y);
            acc.z = fmaf(xv, mw[i].z, acc.z);
            acc.w = fmaf(xv, mw[i].w, acc.w);
        }
        f32x4* dst = reinterpret_cast<f32x4*>(&out[(size_t)(row0 + r) * UNITS + u0]);
        __builtin_nontemporal_store(acc, dst);  // streaming write-once output
    }
}

extern "C" void kernel_launch(void* const* d_in, const int* in_sizes, int n_in,
                              void* d_out, int out_size, void* d_ws, size_t ws_size,
                              hipStream_t stream) {
    const float* x    = (const float*)d_in[0];  // inputs [2048, 15]
    const float* w    = (const float*)d_in[1];  // w      [15, 49152]
    const float* b    = (const float*)d_in[2];  // b      [49152]
    const float* mask = (const float*)d_in[3];  // mask   [49152, 15]
    float* out        = (float*)d_out;          // [2048, 49152]

    dim3 grid(UNITS / U_PER_BLOCK, BATCH / ROWS_PER_BLOCK);  // 48 x 32
    striatum_kernel<<<grid, TPB, 0, stream>>>(x, w, b, mask, out);
}